// Round 9
// baseline (734.552 us; speedup 1.0000x reference)
//
#include <hip/hip_runtime.h>
#include <math.h>

#define N_ROWS 32768
#define DIM 256
#define K_CODES 1024

// ---- workspace float offsets (total ~1.2 MB) ----
#define WS_LOSS   0        // 1024 distributed loss slots
#define WS_NSUM   1024
#define WS_ZZ     2048     // 32768
#define WS_EE     34816    // 1024
#define WS_COUNTS 35840    // 1024
#define WS_ESUM   36864    // 1024*256
#define WS_TOTAL  (36864 + K_CODES * DIM)   // 299008 floats

// ---- output float offsets (return-order concatenation) ----
#define OFF_ZQ    0ull
#define OFF_CODES 8388608ull
#define OFF_LOSS  8421376ull
#define OFF_PERP  8421377ull
#define OFF_ENT   8421378ull
#define OFF_SOFT  8421379ull
#define OFF_NEMB  41975811ull
#define OFF_NCS   42237955ull
#define OFF_NEA   42238979ull

// Scratch-in-out plan:
//   packed z hi/lo planes -> OFF_ZQ region; consumed by k2_fused, then OFF_ZQ
//   rewritten by k3_zq (runs after).
//   packed e hi/lo planes -> OFF_EPACK = OFF_NEMB+1 (16B-aligned); that region
//   is overwritten only later by k4a/k4b.
#define OFF_EPACK 41975812ull
#define PLANE_Z   8388608ull    // 32768*256 bf16 elements per z plane
#define PLANE_E   262144ull     // 1024*256 bf16 elements per e plane

// Fragment-native packed layout (per plane), unit = bf16 element:
//   idx(row,k) = ((row>>4)*8 + (k>>5))*512 + ((((k>>3)&3)*16 + (row&15))*8) + (k&7)

typedef __attribute__((ext_vector_type(8))) short bf16x8;
typedef __attribute__((ext_vector_type(4))) float f32x4;

__device__ __forceinline__ ushort f2bf(float x) {           // fp32 -> bf16 RNE
    union { float f; unsigned u; } a; a.f = x;
    unsigned r = a.u + 0x7fffu + ((a.u >> 16) & 1u);
    return (ushort)(r >> 16);
}
__device__ __forceinline__ float bf2f(ushort h) {
    union { unsigned u; float f; } a; a.u = ((unsigned)h) << 16;
    return a.f;
}

__global__ __launch_bounds__(256) void k0_zero(float* ws) {
    int i = blockIdx.x * 256 + threadIdx.x;
    if (i < WS_TOTAL) ws[i] = 0.0f;
}

// one wave per row: norms AND split-bf16 packed plane extraction (verbatim R7).
__global__ __launch_bounds__(256) void k1_norms(const float* __restrict__ z,
                                                const float* __restrict__ embed,
                                                float* __restrict__ ws,
                                                float* out) {
    ushort* zhi = (ushort*)(out + OFF_ZQ);
    ushort* zlo = zhi + PLANE_Z;
    ushort* ehi = (ushort*)(out + OFF_EPACK);
    ushort* elo = ehi + PLANE_E;

    int wave = threadIdx.x >> 6;
    int lane = threadIdx.x & 63;
    int row = blockIdx.x * 4 + wave;
    const float* src = (row < N_ROWS) ? (z + (size_t)row * DIM)
                                      : (embed + (size_t)(row - N_ROWS) * DIM);
    float4 v = *(const float4*)(src + lane * 4);
    float s = v.x * v.x + v.y * v.y + v.z * v.z + v.w * v.w;

    ushort h0 = f2bf(v.x), h1 = f2bf(v.y), h2 = f2bf(v.z), h3 = f2bf(v.w);
    ushort l0 = f2bf(v.x - bf2f(h0)), l1 = f2bf(v.y - bf2f(h1));
    ushort l2 = f2bf(v.z - bf2f(h2)), l3 = f2bf(v.w - bf2f(h3));
    unsigned hA = (unsigned)h0 | ((unsigned)h1 << 16);
    unsigned hB = (unsigned)h2 | ((unsigned)h3 << 16);
    unsigned lA = (unsigned)l0 | ((unsigned)l1 << 16);
    unsigned lB = (unsigned)l2 | ((unsigned)l3 << 16);

    int r = (row < N_ROWS) ? row : (row - N_ROWS);
    int kb = lane >> 3;
    int lg = (lane >> 1) & 3;
    int j0 = (lane & 1) * 4;
    size_t idx = ((size_t)(r >> 4) * 8 + kb) * 512
               + (size_t)(lg * 16 + (r & 15)) * 8 + j0;

    if (row < N_ROWS) {
        *(uint2*)(zhi + idx) = make_uint2(hA, hB);
        *(uint2*)(zlo + idx) = make_uint2(lA, lB);
    } else {
        *(uint2*)(ehi + idx) = make_uint2(hA, hB);
        *(uint2*)(elo + idx) = make_uint2(lA, lB);
    }

    #pragma unroll
    for (int off = 32; off; off >>= 1) s += __shfl_down(s, off, 64);
    if (lane == 0) {
        if (row < N_ROWS) ws[WS_ZZ + row] = s;
        else              ws[WS_EE + (row - N_ROWS)] = s;
    }
}

// R9: fused MFMA dist-GEMM + argmin + softmax + loss + EMA scatter.
// GEOMETRY FIX vs R8 (which covered only half of K): wave tile = 16 rows x
// 256 cols (fj = 0..15, col = wc*256 + fj*16 + l15 covers [wc*256, wc*256+256)
// exactly); 8 waves = 2 row-groups x 4 col-groups; block = 32 rows x 1024 cols
// (full K). acc[16] f32x4 = 64 floats, same register budget as R7/R8.
// MFMA triple + dist expression verbatim R7. Tie band 1e-3 + fp64 refine
// verbatim R2/R6-passed logic. No zq store here -> k3_zq after.
__global__ __launch_bounds__(512, 2) void k2_fused(const float* __restrict__ z,
                                                   const float* __restrict__ embed,
                                                   float* __restrict__ ws,
                                                   float* __restrict__ out) {
    __shared__ float wmin[8][16];
    __shared__ int   widx[8][16];
    __shared__ float wsum[8][16];
    __shared__ float rowmin_s[32];
    __shared__ int   rowcode_s[32];
    __shared__ float rowinv_s[32];
    __shared__ int   rownc[32];
    __shared__ int   rowcand[32][8];
    __shared__ double sdd[8];
    __shared__ int   anytie;

    const ushort* zhi = (const ushort*)(out + OFF_ZQ);
    const ushort* ehi = (const ushort*)(out + OFF_EPACK);

    int tid  = threadIdx.x;
    int lane = tid & 63;
    int wid  = tid >> 6;
    int wr   = wid >> 2, wc = wid & 3;     // 2 row-groups x 4 col-groups
    int rowBase = blockIdx.x * 32;
    int l15 = lane & 15, lg = lane >> 4;

    f32x4 acc[16];
    #pragma unroll
    for (int fj = 0; fj < 16; ++fj) acc[fj] = (f32x4){0.f, 0.f, 0.f, 0.f};

    int rowBlk = blockIdx.x * 2 + wr;      // packed 16-row block index
    int colBlk = wc * 16;                  // packed 16-col block index base

    for (int kb = 0; kb < 8; ++kb) {
        const ushort* pa = zhi + ((size_t)rowBlk * 8 + kb) * 512 + lane * 8;
        bf16x8 ah = *(const bf16x8*)pa;
        bf16x8 al = *(const bf16x8*)(pa + PLANE_Z);
        #pragma unroll
        for (int fj = 0; fj < 16; ++fj) {
            const ushort* pb = ehi + ((size_t)(colBlk + fj) * 8 + kb) * 512 + lane * 8;
            bf16x8 bh = *(const bf16x8*)pb;
            bf16x8 bl = *(const bf16x8*)(pb + PLANE_E);
            acc[fj] = __builtin_amdgcn_mfma_f32_16x16x32_bf16(ah, bh, acc[fj], 0, 0, 0);
            acc[fj] = __builtin_amdgcn_mfma_f32_16x16x32_bf16(ah, bl, acc[fj], 0, 0, 0);
            acc[fj] = __builtin_amdgcn_mfma_f32_16x16x32_bf16(al, bh, acc[fj], 0, 0, 0);
        }
    }

    // dist in regs: (zz - 2*dot) + ee  (expression verbatim R7).
    // C/D layout (m89): col = wc*256 + fj*16 + l15, row = wr*16 + lg*4 + q.
    #pragma unroll
    for (int q = 0; q < 4; ++q) {
        float zzn = ws[WS_ZZ + rowBase + wr * 16 + lg * 4 + q];
        #pragma unroll
        for (int fj = 0; fj < 16; ++fj) {
            float eek = ws[WS_EE + wc * 256 + fj * 16 + l15];
            acc[fj][q] = (zzn - 2.0f * acc[fj][q]) + eek;
        }
    }

    // per-(lane,row) min over 16 fj, then 16-lane butterfly (lowest-col tiebreak)
    #pragma unroll
    for (int q = 0; q < 4; ++q) {
        float bm = acc[0][q]; int bi = wc * 256 + l15;   // fj asc => col asc
        #pragma unroll
        for (int fj = 1; fj < 16; ++fj) {
            if (acc[fj][q] < bm) { bm = acc[fj][q]; bi = wc * 256 + fj * 16 + l15; }
        }
        #pragma unroll
        for (int m = 1; m <= 8; m <<= 1) {
            float ov = __shfl_xor(bm, m, 64);
            int   oi = __shfl_xor(bi, m, 64);
            if (ov < bm || (ov == bm && oi < bi)) { bm = ov; bi = oi; }
        }
        if (l15 == 0) {
            wmin[wid][lg * 4 + q] = bm;
            widx[wid][lg * 4 + q] = bi;
        }
    }
    if (tid == 0) anytie = 0;
    if (tid < 32) rownc[tid] = 0;
    __syncthreads();
    if (tid < 32) {   // combine 4 col-group waves per row (wc asc, strict <)
        int rw = tid >> 4, rl = tid & 15;
        float bv = wmin[rw * 4][rl]; int bi = widx[rw * 4][rl];
        #pragma unroll
        for (int w = 1; w < 4; ++w) {
            float ov = wmin[rw * 4 + w][rl]; int oi = widx[rw * 4 + w][rl];
            if (ov < bv || (ov == bv && oi < bi)) { bv = ov; bi = oi; }
        }
        rowmin_s[tid] = bv; rowcode_s[tid] = bi;
    }
    __syncthreads();

    float mrow[4];
    #pragma unroll
    for (int q = 0; q < 4; ++q) mrow[q] = rowmin_s[wr * 16 + lg * 4 + q];

    // near-tie candidates (1e-3 band >> split-bf16 dist error ~1e-4)
    #pragma unroll
    for (int q = 0; q < 4; ++q) {
        int r = wr * 16 + lg * 4 + q;
        float thr = mrow[q] + 1e-3f;
        #pragma unroll
        for (int fj = 0; fj < 16; ++fj) {
            if (acc[fj][q] <= thr) {
                int slot = atomicAdd(&rownc[r], 1);
                if (slot < 8) rowcand[r][slot] = wc * 256 + fj * 16 + l15;
            }
        }
    }
    __syncthreads();
    if (tid < 32 && rownc[tid] > 1) atomicAdd(&anytie, 1);
    __syncthreads();
    if (anytie) {    // rare path: fp64 re-dot, numpy-style fp32 final rounding
        for (int r = 0; r < 32; ++r) {
            int nc = rownc[r];
            if (nc <= 1) continue;
            int lim = nc < 8 ? nc : 8;
            int n = rowBase + r;
            float zzn = ws[WS_ZZ + n];
            float bestd = 0.f; int bestk = -1;
            for (int ci = 0; ci < lim; ++ci) {
                int kc = rowcand[r][ci];
                double part = 0.0;
                if (tid < 256)
                    part = (double)z[(size_t)n * DIM + tid] * (double)embed[(size_t)kc * DIM + tid];
                #pragma unroll
                for (int off = 32; off; off >>= 1) part += __shfl_down(part, off, 64);
                if (lane == 0) sdd[wid] = part;
                __syncthreads();
                double dot = 0.0;
                for (int w = 0; w < 8; ++w) dot += sdd[w];
                float d32 = (zzn - 2.0f * (float)dot) + ws[WS_EE + kc];
                if (bestk < 0 || d32 < bestd || (d32 == bestd && kc < bestk)) { bestd = d32; bestk = kc; }
                __syncthreads();
            }
            if (tid == 0) rowcode_s[r] = bestk;
        }
        __syncthreads();
    }

    // softmax: exp in regs, 16-lane butterfly partials, LDS combine, write probs
    #pragma unroll
    for (int q = 0; q < 4; ++q) {
        float m = mrow[q];
        float s = 0.f;
        #pragma unroll
        for (int fj = 0; fj < 16; ++fj) {
            acc[fj][q] = __expf((m - acc[fj][q]) * 10.0f);
            s += acc[fj][q];
        }
        #pragma unroll
        for (int mk = 1; mk <= 8; mk <<= 1) s += __shfl_xor(s, mk, 64);
        if (l15 == 0) wsum[wid][lg * 4 + q] = s;
    }
    __syncthreads();
    if (tid < 32) {
        int rw = tid >> 4, rl = tid & 15;
        float t = wsum[rw * 4][rl] + wsum[rw * 4 + 1][rl]
                + wsum[rw * 4 + 2][rl] + wsum[rw * 4 + 3][rl];
        rowinv_s[tid] = 1.0f / t;
    }
    __syncthreads();
    #pragma unroll
    for (int q = 0; q < 4; ++q) {
        int n = rowBase + wr * 16 + lg * 4 + q;
        float inv = rowinv_s[wr * 16 + lg * 4 + q];
        float* orow = out + OFF_SOFT + (size_t)n * K_CODES;
        #pragma unroll
        for (int fj = 0; fj < 16; ++fj)
            orow[wc * 256 + fj * 16 + l15] = acc[fj][q] * inv;
    }

    // loss + EMA scatter + codes: 16 threads/row, 16 d each (no zq store here)
    {
        int r   = tid >> 4;          // 0..31
        int seg = tid & 15;
        int n = rowBase + r;
        int code = rowcode_s[r];
        int dd = seg * 16;
        float lsum = 0.f;
        #pragma unroll
        for (int qq = 0; qq < 4; ++qq) {
            float4 e4 = *(const float4*)&embed[(size_t)code * DIM + dd + qq * 4];
            float4 z4 = *(const float4*)&z[(size_t)n * DIM + dd + qq * 4];
            float dx = z4.x - e4.x, dy = z4.y - e4.y, dz_ = z4.z - e4.z, dw = z4.w - e4.w;
            lsum += dx * dx + dy * dy + dz_ * dz_ + dw * dw;
            atomicAdd(&ws[WS_ESUM + (size_t)code * DIM + dd + qq * 4 + 0], z4.x);
            atomicAdd(&ws[WS_ESUM + (size_t)code * DIM + dd + qq * 4 + 1], z4.y);
            atomicAdd(&ws[WS_ESUM + (size_t)code * DIM + dd + qq * 4 + 2], z4.z);
            atomicAdd(&ws[WS_ESUM + (size_t)code * DIM + dd + qq * 4 + 3], z4.w);
        }
        #pragma unroll
        for (int off = 8; off; off >>= 1) lsum += __shfl_down(lsum, off, 16);
        if (seg == 0) {
            atomicAdd(&ws[WS_LOSS + (n & 1023)], lsum);
            atomicAdd(&ws[WS_COUNTS + code], 1.0f);
            out[OFF_CODES + n] = (float)code;
        }
    }
}

// zq gather (runs AFTER k2_fused so overwriting the packed z planes is safe)
__global__ __launch_bounds__(256) void k3_zq(const float* __restrict__ embed,
                                             float* __restrict__ out) {
    int wave = threadIdx.x >> 6, lane = threadIdx.x & 63;
    int n = blockIdx.x * 4 + wave;
    int code = (int)out[OFF_CODES + n];
    float4 e4 = *(const float4*)&embed[(size_t)code * DIM + lane * 4];
    *(float4*)&out[OFF_ZQ + (size_t)n * DIM + lane * 4] = e4;
}

__global__ __launch_bounds__(1024) void k4a_stats(const float* __restrict__ cluster_size,
                                                  float* __restrict__ ws,
                                                  float* __restrict__ out) {
    __shared__ float sm[16];
    int k = threadIdx.x;
    int lane = k & 63, wave = k >> 6;
    float cnt = ws[WS_COUNTS + k];
    float ncs = 0.99f * cluster_size[k] + 0.01f * cnt;
    out[OFF_NCS + k] = ncs;

    float v = ncs;
    #pragma unroll
    for (int off = 32; off; off >>= 1) v += __shfl_down(v, off, 64);
    if (lane == 0) sm[wave] = v;
    __syncthreads();
    if (k == 0) {
        float t = 0.f;
        for (int w = 0; w < 16; ++w) t += sm[w];
        ws[WS_NSUM] = t;
    }
    __syncthreads();

    float avg = cnt / (float)N_ROWS;
    v = -avg * logf(avg + 1e-10f);
    #pragma unroll
    for (int off = 32; off; off >>= 1) v += __shfl_down(v, off, 64);
    if (lane == 0) sm[wave] = v;
    __syncthreads();
    if (k == 0) {
        float ent = 0.f;
        for (int w = 0; w < 16; ++w) ent += sm[w];
        out[OFF_ENT]  = ent;
        out[OFF_PERP] = expf(ent);
    }
    __syncthreads();

    v = ws[WS_LOSS + k];
    #pragma unroll
    for (int off = 32; off; off >>= 1) v += __shfl_down(v, off, 64);
    if (lane == 0) sm[wave] = v;
    __syncthreads();
    if (k == 0) {
        float t = 0.f;
        for (int w = 0; w < 16; ++w) t += sm[w];
        out[OFF_LOSS] = t / 8388608.0f;
    }
}

__global__ __launch_bounds__(256) void k4b_embed(const float* __restrict__ embed_avg,
                                                 const float* __restrict__ ws,
                                                 float* __restrict__ out) {
    int k = blockIdx.x, d = threadIdx.x;
    float es  = ws[WS_ESUM + (size_t)k * DIM + d];
    float nea = 0.99f * embed_avg[(size_t)k * DIM + d] + 0.01f * es;
    out[OFF_NEA + (size_t)k * DIM + d] = nea;
    float ncs  = out[OFF_NCS + k];
    float nsum = ws[WS_NSUM];
    float csn  = (ncs + 1e-5f) / (nsum + K_CODES * 1e-5f) * nsum;
    out[OFF_NEMB + (size_t)k * DIM + d] = nea / csn;
}

extern "C" void kernel_launch(void* const* d_in, const int* in_sizes, int n_in,
                              void* d_out, int out_size, void* d_ws, size_t ws_size,
                              hipStream_t stream) {
    const float* z            = (const float*)d_in[0];
    const float* embed        = (const float*)d_in[1];
    const float* cluster_size = (const float*)d_in[2];
    const float* embed_avg    = (const float*)d_in[3];
    float* out = (float*)d_out;
    float* ws  = (float*)d_ws;

    k0_zero<<<(WS_TOTAL + 255) / 256, 256, 0, stream>>>(ws);
    k1_norms<<<(N_ROWS + K_CODES) / 4, 256, 0, stream>>>(z, embed, ws, out);
    k2_fused<<<N_ROWS / 32, 512, 0, stream>>>(z, embed, ws, out);
    k3_zq<<<N_ROWS / 4, 256, 0, stream>>>(embed, out);
    k4a_stats<<<1, 1024, 0, stream>>>(cluster_size, ws, out);
    k4b_embed<<<K_CODES, 256, 0, stream>>>(embed_avg, ws, out);
}